// Round 8
// baseline (309.587 us; speedup 1.0000x reference)
//
#include <hip/hip_runtime.h>

// WindowAttention: x(128,256,512) -> qkv -> windowed attn (epeg conv on Q
// fused as attn prologue; barrier-free main loop, swapped-QK^T lane-local
// online softmax) -> proj.
//
// GEMMs use the 256x256 8-phase schedule (T1 XCD-chunk + T2 both-sides LDS
// swizzle + T3/T4 counted-vmcnt pipeline + T5 setprio), BK=64, 8 waves,
// 128 KiB LDS double buffer, K=512 (NT=8 K-tiles). MM16 computes TRANSPOSED
// fragments (mfma(b,a)): lane owns token (cx) x 4 consecutive cols.
// gemm_qkv epilogue: transposed acc -> LDS stage (ds_write_b64 + cvt_pk,
// r&7-keyed swizzle) -> contiguous 32KB slab stores.
// attn prologue: Q staged into the dead KfPs region (qconv's proven 256x72
// layout), 15-tap conv in registers, in-place writeback, fragments read from
// LDS -> standalone qconv kernel (launch + 64MB HBM round-trip) deleted.
//
// ws layout (bytes):
//   [0)          xbf   33,554,432  (x bf16; REUSED as attnout after gemm_qkv)
//   [33554432)   w1     1,572,864  (qkv_w bf16)
//   [35127296)   w2       524,288  (proj_w bf16)
//   [35651584)   qb    33,554,432  (q scaled (b,h,n,d); conv applied in attn)
//   [69206016)   kb    33,554,432  ((b,h,m,d))
//   [102760448)  vb    33,554,432  (V row-major (b,h,n,d))

typedef unsigned short u16;
typedef unsigned int u32;
typedef __attribute__((ext_vector_type(8))) short short8;   // 8 bf16 (4 VGPRs)
typedef __attribute__((ext_vector_type(4))) float f32x4;

__device__ __forceinline__ u16 f2bf(float f) {
  union { float f; u32 u; } v; v.f = f;
  return (u16)((v.u + 0x7FFFu + ((v.u >> 16) & 1u)) >> 16);  // RNE
}
__device__ __forceinline__ float bf2f(u16 s) {
  union { u32 u; float f; } v; v.u = ((u32)s) << 16;
  return v.f;
}
__device__ __forceinline__ u32 cvtpk(float lo, float hi) {   // RNE pack 2xbf16
  u32 r;
  asm("v_cvt_pk_bf16_f32 %0, %1, %2" : "=v"(r) : "v"(lo), "v"(hi));
  return r;
}

__device__ __forceinline__ void gl2lds16(const u16* g, u16* l) {
  __builtin_amdgcn_global_load_lds((const __attribute__((address_space(1))) void*)g,
                                   (__attribute__((address_space(3))) void*)l, 16, 0, 0);
}

// fragment cell address (u16 units) with bank-spreading XOR swizzle (attn)
__device__ __forceinline__ int fragaddr(int frag, int lane) {
  return (frag * 64 + (lane ^ (frag & 7))) * 8;
}

// ---------------- fp32 -> bf16 conversion ------------------------------------
__global__ __launch_bounds__(256) void cvt_all(
    const float* __restrict__ x, const float* __restrict__ w1f,
    const float* __restrict__ w2f, u16* __restrict__ xo,
    u16* __restrict__ w1o, u16* __restrict__ w2o) {
  const int NX = 4194304, NW1 = 196608, NW2 = 65536;
  int i = blockIdx.x * 256 + threadIdx.x;
  const float* src; u16* dst; int j;
  if (i < NX)                  { src = x;   dst = xo;  j = i; }
  else if (i < NX + NW1)       { src = w1f; dst = w1o; j = i - NX; }
  else if (i < NX + NW1 + NW2) { src = w2f; dst = w2o; j = i - NX - NW1; }
  else return;
  float4 f = ((const float4*)src)[j];
  uint2 o;
  o.x = (u32)f2bf(f.x) | ((u32)f2bf(f.y) << 16);
  o.y = (u32)f2bf(f.z) | ((u32)f2bf(f.w) << 16);
  ((uint2*)dst)[j] = o;
}

// ---------------- 256x256 8-phase GEMM core (TRANSPOSED acc) -----------------
// C = A[256x512] * B[256x512]^T; acc[mf][nf] holds the transposed D fragment:
// element [i] = C[token = wm*128+mf*16+cx][col = wn*64+nf*16+g*4+i].
__device__ __forceinline__ void gemm256_core(
    const u16* __restrict__ A, const u16* __restrict__ B,
    int m0, int n0, u16* lds, f32x4 acc[8][4]) {
  const int NT = 8;                       // K = 512, BK = 64
  int tid = threadIdx.x, wave = tid >> 6, lane = tid & 63;
  int wm = wave >> 2, wn = wave & 3;

  int ch0 = tid, ch1 = tid + 512;
  int row0 = ch0 >> 2, row1 = ch1 >> 2;
  int cg0 = (ch0 & 3) ^ (row0 & 3) ^ ((row0 >> 2) & 3);
  int cg1 = (ch1 & 3) ^ (row1 & 3) ^ ((row1 >> 2) & 3);
  const u16* Ag0 = A + (size_t)(m0 + row0) * 512 + cg0 * 8;
  const u16* Ag1 = A + (size_t)(m0 + row1) * 512 + cg1 * 8;
  const u16* Bg0 = B + (size_t)(n0 + row0) * 512 + cg0 * 8;
  const u16* Bg1 = B + (size_t)(n0 + row1) * 512 + cg1 * 8;
  int ldsu0 = wave * 64 * 8;              // HW adds lane*16B
  int ldsu1 = (512 + wave * 64) * 8;

  int frag_off = (lane & 15) * 32 +
                 (((lane >> 4) ^ (lane & 3) ^ ((lane >> 2) & 3)) << 3);
  int abase = wm * 4096 + frag_off;        // + mf*512 + kh*16384 + p*32768
  int bbase = 8192 + wn * 2048 + frag_off; // + nf*512 + kh*16384 + p*32768

#define STAGE(h)                                                             \
  do {                                                                       \
    if ((h) < NT * 4) {                                                      \
      int T_ = (h) >> 2, kh_ = ((h) >> 1) & 1, isB_ = (h) & 1;               \
      int ko_ = T_ * 64 + kh_ * 32;                                          \
      u16* d_ = lds + (T_ & 1) * 32768 + kh_ * 16384 + isB_ * 8192;          \
      gl2lds16((isB_ ? Bg0 : Ag0) + ko_, d_ + ldsu0);                        \
      gl2lds16((isB_ ? Bg1 : Ag1) + ko_, d_ + ldsu1);                        \
    }                                                                        \
  } while (0)

#define LDA(dst, mf, kh, p)                                                  \
  dst = *(const short8*)(lds + (p) * 32768 + (kh) * 16384 + abase + (mf) * 512)
#define LDB(dst, nf, kh, p)                                                  \
  dst = *(const short8*)(lds + (p) * 32768 + (kh) * 16384 + bbase + (nf) * 512)

// transposed: acc[m][n] = mfma(b_n, a_m, acc[m][n])
#define MM16(M0)                                                                                   \
  __builtin_amdgcn_s_setprio(1);                                                                   \
  acc[(M0)+0][0] = __builtin_amdgcn_mfma_f32_16x16x32_bf16(b0, a0, acc[(M0)+0][0], 0, 0, 0);       \
  acc[(M0)+0][1] = __builtin_amdgcn_mfma_f32_16x16x32_bf16(b1, a0, acc[(M0)+0][1], 0, 0, 0);       \
  acc[(M0)+0][2] = __builtin_amdgcn_mfma_f32_16x16x32_bf16(b2, a0, acc[(M0)+0][2], 0, 0, 0);       \
  acc[(M0)+0][3] = __builtin_amdgcn_mfma_f32_16x16x32_bf16(b3, a0, acc[(M0)+0][3], 0, 0, 0);       \
  acc[(M0)+1][0] = __builtin_amdgcn_mfma_f32_16x16x32_bf16(b0, a1, acc[(M0)+1][0], 0, 0, 0);       \
  acc[(M0)+1][1] = __builtin_amdgcn_mfma_f32_16x16x32_bf16(b1, a1, acc[(M0)+1][1], 0, 0, 0);       \
  acc[(M0)+1][2] = __builtin_amdgcn_mfma_f32_16x16x32_bf16(b2, a1, acc[(M0)+1][2], 0, 0, 0);       \
  acc[(M0)+1][3] = __builtin_amdgcn_mfma_f32_16x16x32_bf16(b3, a1, acc[(M0)+1][3], 0, 0, 0);       \
  acc[(M0)+2][0] = __builtin_amdgcn_mfma_f32_16x16x32_bf16(b0, a2, acc[(M0)+2][0], 0, 0, 0);       \
  acc[(M0)+2][1] = __builtin_amdgcn_mfma_f32_16x16x32_bf16(b1, a2, acc[(M0)+2][1], 0, 0, 0);       \
  acc[(M0)+2][2] = __builtin_amdgcn_mfma_f32_16x16x32_bf16(b2, a2, acc[(M0)+2][2], 0, 0, 0);       \
  acc[(M0)+2][3] = __builtin_amdgcn_mfma_f32_16x16x32_bf16(b3, a2, acc[(M0)+2][3], 0, 0, 0);       \
  acc[(M0)+3][0] = __builtin_amdgcn_mfma_f32_16x16x32_bf16(b0, a3, acc[(M0)+3][0], 0, 0, 0);       \
  acc[(M0)+3][1] = __builtin_amdgcn_mfma_f32_16x16x32_bf16(b1, a3, acc[(M0)+3][1], 0, 0, 0);       \
  acc[(M0)+3][2] = __builtin_amdgcn_mfma_f32_16x16x32_bf16(b2, a3, acc[(M0)+3][2], 0, 0, 0);       \
  acc[(M0)+3][3] = __builtin_amdgcn_mfma_f32_16x16x32_bf16(b3, a3, acc[(M0)+3][3], 0, 0, 0);       \
  __builtin_amdgcn_s_setprio(0)

  STAGE(0); STAGE(1); STAGE(2); STAGE(3); STAGE(4);
  asm volatile("s_waitcnt vmcnt(6)" ::: "memory");
  __builtin_amdgcn_s_barrier();

#pragma unroll 1
  for (int kt = 0; kt < NT; ++kt) {
    int p = kt & 1;
    int hb = kt * 4 + 5;
    short8 a0, a1, a2, a3, b0, b1, b2, b3;
    LDA(a0, 0, 0, p); LDA(a1, 1, 0, p); LDA(a2, 2, 0, p); LDA(a3, 3, 0, p);
    LDB(b0, 0, 0, p); LDB(b1, 1, 0, p); LDB(b2, 2, 0, p); LDB(b3, 3, 0, p);
    STAGE(hb);
    __builtin_amdgcn_s_barrier();
    asm volatile("s_waitcnt lgkmcnt(0)" ::: "memory");
    MM16(0);
    __builtin_amdgcn_s_barrier();
    LDA(a0, 4, 0, p); LDA(a1, 5, 0, p); LDA(a2, 6, 0, p); LDA(a3, 7, 0, p);
    STAGE(hb + 1);
    __builtin_amdgcn_s_barrier();
    asm volatile("s_waitcnt lgkmcnt(0)" ::: "memory");
    MM16(4);
    if (kt == NT - 1) asm volatile("s_waitcnt vmcnt(0)" ::: "memory");
    else              asm volatile("s_waitcnt vmcnt(6)" ::: "memory");
    __builtin_amdgcn_s_barrier();
    LDA(a0, 0, 1, p); LDA(a1, 1, 1, p); LDA(a2, 2, 1, p); LDA(a3, 3, 1, p);
    LDB(b0, 0, 1, p); LDB(b1, 1, 1, p); LDB(b2, 2, 1, p); LDB(b3, 3, 1, p);
    STAGE(hb + 2);
    __builtin_amdgcn_s_barrier();
    asm volatile("s_waitcnt lgkmcnt(0)" ::: "memory");
    MM16(0);
    __builtin_amdgcn_s_barrier();
    LDA(a0, 4, 1, p); LDA(a1, 5, 1, p); LDA(a2, 6, 1, p); LDA(a3, 7, 1, p);
    STAGE(hb + 3);
    __builtin_amdgcn_s_barrier();
    asm volatile("s_waitcnt lgkmcnt(0)" ::: "memory");
    MM16(4);
    if (kt == NT - 2)     asm volatile("s_waitcnt vmcnt(4)" ::: "memory");
    else if (kt < NT - 2) asm volatile("s_waitcnt vmcnt(6)" ::: "memory");
    __builtin_amdgcn_s_barrier();
  }
#undef STAGE
#undef LDA
#undef LDB
#undef MM16
}

// ---------------- GEMM1: qkv = x @ qkv_w^T + b; scatter q(scaled)/k/v --------
__global__ __launch_bounds__(512, 2) void gemm_qkv256(
    const u16* __restrict__ A, const u16* __restrict__ B,
    const float* __restrict__ qkvb, u16* __restrict__ qb,
    u16* __restrict__ kb, u16* __restrict__ vb) {
  __shared__ __align__(16) u16 lds[65536];   // 128 KiB
  f32x4 acc[8][4];
#pragma unroll
  for (int a = 0; a < 8; ++a)
#pragma unroll
    for (int c = 0; c < 4; ++c) acc[a][c] = (f32x4){0.f, 0.f, 0.f, 0.f};
  // XCD-chunked bijective swizzle (768 % 8 == 0)
  int bid = blockIdx.x;
  int wg = (bid & 7) * 96 + (bid >> 3);
  int m0 = (wg / 6) * 256, n0 = (wg % 6) * 256;
  gemm256_core(A, B, m0, n0, lds, acc);

  int tid = threadIdx.x, wave = tid >> 6, lane = tid & 63;
  int wm = wave >> 2, wn = wave & 3;
  int cx = lane & 15, g = lane >> 4;

  // ---- stage C tile in LDS: one b64 write per (mf,nf) ----
  __syncthreads();
  float sc = (n0 < 512) ? 0.125f : 1.f;      // q-scale, uniform per tile
  float4 bvn[4];
#pragma unroll
  for (int nf = 0; nf < 4; ++nf)
    bvn[nf] = *(const float4*)(qkvb + n0 + wn * 64 + nf * 16 + g * 4);
#pragma unroll
  for (int mf = 0; mf < 8; ++mf) {
    int r = wm * 128 + mf * 16 + cx;
    int swz = r & 7;                         // low row bits -> 2-way only
#pragma unroll
    for (int nf = 0; nf < 4; ++nf) {
      int c0 = wn * 64 + nf * 16 + g * 4;    // 4 consecutive cols
      int c16 = (c0 >> 3) ^ swz;
      f32x4 v = acc[mf][nf];
      u32 w0 = cvtpk((v[0] + bvn[nf].x) * sc, (v[1] + bvn[nf].y) * sc);
      u32 w1 = cvtpk((v[2] + bvn[nf].z) * sc, (v[3] + bvn[nf].w) * sc);
      *(uint2*)(lds + r * 256 + c16 * 8 + (c0 & 7)) = make_uint2(w0, w1);
    }
  }
  __syncthreads();

  // ---- copy-out: 4 h-group slabs, each 256n x 64d contiguous --------------
  int b = m0 >> 8;                           // tile is one window
  int nrow = tid >> 3, dc = tid & 7;
#pragma unroll
  for (int j = 0; j < 16; ++j) {
    const int hg = j >> 2;
    int gcol = n0 + hg * 64;
    int which = gcol >> 9;
    int h = (gcol >> 6) & 7;
    u16* dst = (which == 0 ? qb : (which == 1 ? kb : vb)) +
               (size_t)(b * 8 + h) * 16384;
    int n = (j & 3) * 64 + nrow;
    int c16 = (hg * 8 + dc) ^ (n & 7);
    uint4 val = *(const uint4*)(lds + n * 256 + c16 * 8);
    *(uint4*)(dst + n * 64 + dc * 8) = val;
  }
}

// ---------------- GEMM2: out = attnout @ proj_w^T + proj_b (fp32 out) --------
__global__ __launch_bounds__(512, 2) void gemm_proj256(
    const u16* __restrict__ A, const u16* __restrict__ B,
    const float* __restrict__ pb, float* __restrict__ out) {
  __shared__ __align__(16) u16 lds[65536];   // 128 KiB
  f32x4 acc[8][4];
#pragma unroll
  for (int a = 0; a < 8; ++a)
#pragma unroll
    for (int c = 0; c < 4; ++c) acc[a][c] = (f32x4){0.f, 0.f, 0.f, 0.f};
  int bid = blockIdx.x;
  int wg = (bid & 7) * 32 + (bid >> 3);      // 256 % 8 == 0, bijective
  int m0 = (wg >> 1) * 256, n0 = (wg & 1) * 256;
  gemm256_core(A, B, m0, n0, lds, acc);

  int tid = threadIdx.x, wave = tid >> 6, lane = tid & 63;
  int wm = wave >> 2, wn = wave & 3;
  int cx = lane & 15, g = lane >> 4;
  int cb = n0 + wn * 64 + g * 4;
  float4 bv[4];
#pragma unroll
  for (int nf = 0; nf < 4; ++nf) bv[nf] = *(const float4*)(pb + cb + nf * 16);
  int r0 = m0 + wm * 128 + cx;
#pragma unroll
  for (int mf = 0; mf < 8; ++mf) {
    size_t rb = (size_t)(r0 + mf * 16) * 512;
#pragma unroll
    for (int nf = 0; nf < 4; ++nf) {
      f32x4 v = acc[mf][nf];
      float4 o = make_float4(v[0] + bv[nf].x, v[1] + bv[nf].y,
                             v[2] + bv[nf].z, v[3] + bv[nf].w);
      *(float4*)(out + rb + cb + nf * 16) = o;
    }
  }
}

// ---------------- attention: 1 wg (512 thr) per (b,h); barrier-free loop -----
// Prologue fuses the epeg conv (qconv's algorithm): Q staged into the dead
// KfPs region (256x72, 16B-aligned rows), 15-tap conv in 32 static registers,
// in-place writeback, Q fragments read from LDS. Then the original flow:
// V->Vtmp (overwrites Ql), Vf build, Kf write, barrier-free main loop with
// swapped QK^T AND swapped PV; softmax state and O in the q=cx lane domain.
__global__ __launch_bounds__(512, 2) void attn_win(
    const u16* __restrict__ qb, const u16* __restrict__ kb,
    const u16* __restrict__ vb, const float* __restrict__ pe_w,
    const float* __restrict__ pe_b, const float* __restrict__ rpb,
    u16* __restrict__ attnout) {
  __shared__ __align__(16) u16 KfPs[21504];   // Ql(18432) -> Vtmp -> Kf+Ps
  __shared__ __align__(16) u16 Vf[16384];     // 32 frags (dt,km), fragment-ordered
  __shared__ float biasl[961];
  __shared__ float wsh[15];

  int bh = blockIdx.x, b = bh >> 3, h = bh & 7;
  int tid = threadIdx.x, wave = tid >> 6, lane = tid & 63;
  int cx = lane & 15, g = lane >> 4;

  const uint4* kg = (const uint4*)(kb + (size_t)bh * 16384);
  const uint4* vg = (const uint4*)(vb + (size_t)bh * 16384);
  const uint4* qg = (const uint4*)(qb + (size_t)bh * 16384);

  // K prefetch into registers (KfPs is occupied by Ql/Vtmp until Vf built)
  uint4 kreg[4];
#pragma unroll
  for (int it = 0; it < 4; ++it) kreg[it] = kg[tid + it * 512];

  // ---- phase Q: stage Q rows -> Ql (stride 72; qconv's proven layout) ----
  u16* Ql = KfPs;
#pragma unroll
  for (int it = 0; it < 4; ++it) {
    int idx = tid + it * 512;
    int row = idx >> 3, c = (idx & 7) * 8;
    *(uint4*)(Ql + row * 72 + c) = qg[idx];
  }
  if (tid < 15) wsh[tid] = pe_w[h * 15 + tid] + (tid == 7 ? 1.f : 0.f);  // identity folded
  {
    float peb = pe_b[h];
    for (int i = tid; i < 961; i += 512) biasl[i] = rpb[i * 8 + h] + peb;
  }
  __syncthreads();

  // ---- conv15 along tokens into registers (qconv algorithm, 512-thr split) --
  int dg = (tid & 15) * 4, nb = tid >> 4;      // nb in 0..31
  float ca[8][4];
#pragma unroll
  for (int i = 0; i < 8; ++i) {
    int n = nb + i * 32;
    float a0 = 0.f, a1 = 0.f, a2 = 0.f, a3 = 0.f;
#pragma unroll
    for (int t = 0; t < 15; ++t) {
      int nn = n + t - 7;
      if (nn < 0 || nn > 255) continue;
      uint2 rv = *(const uint2*)(Ql + nn * 72 + dg);
      float wt = wsh[t];
      a0 += wt * bf2f(rv.x & 0xffff); a1 += wt * bf2f(rv.x >> 16);
      a2 += wt * bf2f(rv.y & 0xffff); a3 += wt * bf2f(rv.y >> 16);
    }
    ca[i][0] = a0; ca[i][1] = a1; ca[i][2] = a2; ca[i][3] = a3;
  }
  __syncthreads();
  // write conv'd Q back in place (RNE pack, identical numerics to qconv)
#pragma unroll
  for (int i = 0; i < 8; ++i) {
    int n = nb + i * 32;
    uint2 pv;
    pv.x = cvtpk(ca[i][0], ca[i][1]);
    pv.y = cvtpk(ca[i][2], ca[i][3]);
    *(uint2*)(Ql + n * 72 + dg) = pv;
  }
  __syncthreads();

  // ---- read conv'd Q fragments for both it2 from Ql ----
  short8 qfr0a = *(const short8*)(Ql + (0 * 128 + wave * 16 + cx) * 72 + g * 8);
  short8 qfr0b = *(const short8*)(Ql + (0 * 128 + wave * 16 + cx) * 72 + 32 + g * 8);
  short8 qfr1a = *(const short8*)(Ql + (1 * 128 + wave * 16 + cx) * 72 + g * 8);
  short8 qfr1b = *(const short8*)(Ql + (1 * 128 + wave * 16 + cx) * 72 + 32 + g * 8);
  __syncthreads();   // frag reads complete before V-staging overwrites Ql

  // ---- stage V rows -> Vtmp (stride 68, bank-spread) ----
  u16* Vtmp = KfPs;
#pragma unroll
  for (int it = 0; it < 4; ++it) {
    int idx = tid + it * 512;
    uint4 v = vg[idx];
    int row = idx >> 3, c8 = (idx & 7) * 8;
    *(uint2*)(Vtmp + row * 68 + c8)     = make_uint2(v.x, v.y);
    *(uint2*)(Vtmp + row * 68 + c8 + 4) = make_uint2(v.z, v.w);
  }
  __syncthreads();

  // ---- build Vf fragments (transpose): frag(dt,km), lane holds V[m..m+7][d] --
#pragma unroll
  for (int it = 0; it < 4; ++it) {
    int o = tid + it * 512;
    int frag = o >> 6, lanep = o & 63;
    int d = (frag >> 3) * 16 + (lanep & 15);
    int mb = (frag & 7) * 32 + (lanep >> 4) * 8;
    uint4 pk;
    pk.x = (u32)Vtmp[(mb + 0) * 68 + d] | ((u32)Vtmp[(mb + 1) * 68 + d] << 16);
    pk.y = (u32)Vtmp[(mb + 2) * 68 + d] | ((u32)Vtmp[(mb + 3) * 68 + d] << 16);
    pk.z = (u32)Vtmp[(mb + 4) * 68 + d] | ((u32)Vtmp[(mb + 5) * 68 + d] << 16);
    pk.w = (u32)Vtmp[(mb + 6) * 68 + d] | ((u32)Vtmp[(mb + 7) * 68 + d] << 16);
    *(uint4*)(Vf + (frag * 64 + (lanep ^ (frag & 7))) * 8) = pk;
  }
  __syncthreads();

  // ---- write K fragments from registers ----
  u16* Kf = KfPs;
#pragma unroll
  for (int it = 0; it < 4; ++it) {
    int idx = tid + it * 512;
    int n = idx >> 3, k8 = idx & 7;
    int frag = (n >> 4) * 2 + (k8 >> 2);
    int lanep = (n & 15) + 16 * (k8 & 3);
    *(uint4*)(Kf + (frag * 64 + (lanep ^ (frag & 7))) * 8) = kreg[it];
  }
  __syncthreads();   // last barrier — main loop is barrier-free

  u16* Psw = KfPs + 16384 + wave * 640;

#pragma unroll
  for (int it2 = 0; it2 < 2; ++it2) {
    short8 qf0 = it2 ? qfr1a : qfr0a;
    short8 qf1 = it2 ? qfr1b : qfr0b;
    int qbase = it2 * 128 + wave * 16;

    float m_run = -1e30f, l_run = 0.f;
    f32x4 oacc[4];
#pragma unroll
    for (int dt = 0; dt < 4; ++dt) oacc[dt] = (f32x4){0.f, 0.f, 0.f, 0.f};

#pragma unroll
    for (int c = 0; c < 2; ++c) {
      // ---- QK^T (swapped): acc[mt] = S^T rows k, cols q=cx ----
      f32x4 acc[8];
#pragma unroll
      for (int mt = 0; mt < 8; ++mt) acc[mt] = (f32x4){0.f, 0.f, 0.f, 0.f};
      __builtin_amdgcn_s_setprio(1);
#pragma unroll
      for (int mt = 0; mt < 8; ++mt) {
        int fr = (c * 8 + mt) * 2;
        short8 k0 = *(const short8*)(Kf + fragaddr(fr, lane));
        short8 k1 = *(const short8*)(Kf + fragaddr(fr + 1, lane));
        acc[mt] = __builtin_amdgcn_mfma_f32_16x16x32_bf16(k0, qf0, acc[mt], 0, 0, 0);
        acc[mt] = __builtin_amdgcn_mfma_f32_16x16x32_bf16(k1, qf1, acc[mt], 0, 0, 0);
      }
      __builtin_amdgcn_s_setprio(0);

      // ---- bias add (lane-local k) ----
      // k = c*128 + mt*16 + g*4 + i ; q = qbase + cx
      int nb2 = (it2 * 8 + wave - c * 8 + 15) * 31 + cx - g * 4 + 15;
#pragma unroll
      for (int mt = 0; mt < 8; ++mt) {
        const float* bp = biasl + (nb2 - 31 * mt);
        acc[mt][0] += bp[0];  acc[mt][1] += bp[-1];
        acc[mt][2] += bp[-2]; acc[mt][3] += bp[-3];
      }

      // ---- online softmax: lane-local tree + 2 shfl ----
      float mx = fmaxf(fmaxf(acc[0][0], acc[0][1]), fmaxf(acc[0][2], acc[0][3]));
#pragma unroll
      for (int mt = 1; mt < 8; ++mt)
        mx = fmaxf(mx, fmaxf(fmaxf(acc[mt][0], acc[mt][1]),
                             fmaxf(acc[mt][2], acc[mt][3])));
      mx = fmaxf(mx, __shfl_xor(mx, 16));
      mx = fmaxf(mx, __shfl_xor(mx, 32));
      float mnew = fmaxf(m_run, mx);
      float al = __expf(m_run - mnew);
      float s = 0.f;
#pragma unroll
      for (int mt = 0; mt < 8; ++mt)
#pragma unroll
        for (int i = 0; i < 4; ++i) {
          float e = __expf(acc[mt][i] - mnew);
          acc[mt][i] = e; s += e;
        }
      s += __shfl_xor(s, 16);
      s += __shfl_xor(s, 32);
      l_run = l_run * al + s;
      m_run = mnew;

      // alpha rescale: oacc cols are q=cx -> lane-local, no shuffles
#pragma unroll
      for (int dt = 0; dt < 4; ++dt)
#pragma unroll
        for (int i = 0; i < 4; ++i) oacc[dt][i] *= al;

      // ---- PV (swapped): oacc[dt] rows = d, cols = q=cx ----
#pragma unroll
      for (int kk = 0; kk < 4; ++kk) {
        u32 w0 = cvtpk(acc[2 * kk][0], acc[2 * kk][1]);
        u32 w1 = cvtpk(acc[2 * kk][2], acc[2 * kk][3]);
        u32 w2 = cvtpk(acc[2 * kk + 1][0], acc[2 * kk + 1][1]);
        u32 w3 = cvtpk(acc[2 * kk + 1][2], acc[2 * kk + 1][3]);
        *(uint2*)(Psw + cx * 40 + g * 4)      = make_uint2(w0, w1);
        *(uint2*)(Psw + cx * 40 + 16 + g * 4) = make_uint2(w2, w3);
        short8 pa = *(const short8*)(Psw + cx * 40 + g * 8);
        __builtin_amdgcn_s_setprio(1);
#pragma unroll
        for (int dt = 0; dt < 4; ++dt) {
          short8 vf = *(const short8*)(Vf + fragaddr(dt * 8 + c * 4 + kk, lane));
          oacc[dt] = __builtin_amdgcn_mfma_f32_16x16x32_bf16(vf, pa, oacc[dt], 0, 0, 0);
        }
        __builtin_amdgcn_s_setprio(0);
      }
    }

    // ---- epilogue: normalize (lane-local) + packed store ----
    float inv = 1.f / l_run;
    u16* ao = attnout + ((size_t)b * 256 + qbase + cx) * 512 + h * 64;
#pragma unroll
    for (int dt = 0; dt < 4; ++dt) {
      u32 w0 = cvtpk(oacc[dt][0] * inv, oacc[dt][1] * inv);
      u32 w1 = cvtpk(oacc[dt][2] * inv, oacc[dt][3] * inv);
      *(uint2*)(ao + dt * 16 + g * 4) = make_uint2(w0, w1);
    }
  }
}

extern "C" void kernel_launch(void* const* d_in, const int* in_sizes, int n_in,
                              void* d_out, int out_size, void* d_ws, size_t ws_size,
                              hipStream_t stream) {
  const float* x      = (const float*)d_in[0];
  const float* qkv_w  = (const float*)d_in[1];
  const float* qkv_b  = (const float*)d_in[2];
  const float* pe_w   = (const float*)d_in[3];
  const float* pe_b   = (const float*)d_in[4];
  const float* rpb    = (const float*)d_in[5];
  const float* proj_w = (const float*)d_in[6];
  const float* proj_b = (const float*)d_in[7];
  float* out = (float*)d_out;
  char* ws = (char*)d_ws;

  size_t off = 0;
  u16* xbf = (u16*)(ws + off); off += (size_t)16777216 * 2;  // also attnout
  u16* w1  = (u16*)(ws + off); off += (size_t)786432 * 2;
  u16* w2  = (u16*)(ws + off); off += (size_t)262144 * 2;
  u16* qb  = (u16*)(ws + off); off += (size_t)16777216 * 2;
  u16* kb  = (u16*)(ws + off); off += (size_t)16777216 * 2;
  u16* vb  = (u16*)(ws + off); off += (size_t)16777216 * 2;

  hipLaunchKernelGGL(cvt_all, dim3(17408), dim3(256), 0, stream,
                     x, qkv_w, proj_w, xbf, w1, w2);
  hipLaunchKernelGGL(gemm_qkv256, dim3(768), dim3(512), 0, stream,
                     xbf, w1, qkv_b, qb, kb, vb);
  hipLaunchKernelGGL(attn_win, dim3(1024), dim3(512), 0, stream,
                     qb, kb, vb, pe_w, pe_b, rpb, xbf);
  hipLaunchKernelGGL(gemm_proj256, dim3(256), dim3(512), 0, stream,
                     xbf, w2, proj_b, out);
}

// Round 9
// 300.194 us; speedup vs baseline: 1.0313x; 1.0313x over previous
//
#include <hip/hip_runtime.h>

// WindowAttention: x(128,256,512) -> qkv -> qconv -> windowed attn
// (barrier-free, swapped-QK^T lane-local online softmax, lane-local K=16 PV)
// -> proj.
//
// GEMMs: 256x256 8-phase schedule (T1 XCD-chunk + T2 both-sides LDS swizzle +
// T3/T4 counted-vmcnt + T5 setprio), BK=64, 8 waves, 128 KiB LDS dbuf,
// TRANSPOSED MM16 (mfma(b,a)); gemm_qkv epilogue stages via ds_write_b64 +
// cvt_pk (r&7-keyed swizzle) then 32KB slab stores.
// attn: swapped QK^T gives lane (cx,g) the S^T rows k=mt*16+g*4+i for q=cx —
// exactly the B-operand layout of mfma_f32_16x16x16_bf16, so PV runs K=16
// with P packed IN-REGISTER (cvt_pk x2) and NO LDS roundtrip (the old
// Psw write->read RAW chain, ~250cy x16/block, is deleted). Vf is stored in
// the K=16 A-fragment layout (uint2 per lane per frag, linear, conflict-free).
// qconv stays standalone (fusing it cost +25us in gemm [r5] and +20us in
// attn [r8] — it wants an uncontended kernel).
//
// ws layout (bytes):
//   [0)          xbf   33,554,432  (x bf16; REUSED as attnout after gemm_qkv)
//   [33554432)   w1     1,572,864  (qkv_w bf16)
//   [35127296)   w2       524,288  (proj_w bf16)
//   [35651584)   qb    33,554,432  (q scaled (b,h,n,d); conv'd in place)
//   [69206016)   kb    33,554,432  ((b,h,m,d))
//   [102760448)  vb    33,554,432  (V row-major (b,h,n,d))

typedef unsigned short u16;
typedef unsigned int u32;
typedef __attribute__((ext_vector_type(8))) short short8;   // 8 bf16 (4 VGPRs)
typedef __attribute__((ext_vector_type(4))) short s4b;      // 4 bf16 (2 VGPRs)
typedef __attribute__((ext_vector_type(4))) float f32x4;

__device__ __forceinline__ u16 f2bf(float f) {
  union { float f; u32 u; } v; v.f = f;
  return (u16)((v.u + 0x7FFFu + ((v.u >> 16) & 1u)) >> 16);  // RNE
}
__device__ __forceinline__ float bf2f(u16 s) {
  union { u32 u; float f; } v; v.u = ((u32)s) << 16;
  return v.f;
}
__device__ __forceinline__ u32 cvtpk(float lo, float hi) {   // RNE pack 2xbf16
  u32 r;
  asm("v_cvt_pk_bf16_f32 %0, %1, %2" : "=v"(r) : "v"(lo), "v"(hi));
  return r;
}

// K=16 bf16 MFMA (A,B: 4 bf16 = 2 VGPRs; C/D layout same as 16x16x32)
__device__ __forceinline__ f32x4 mfma16(s4b a, s4b b, f32x4 c) {
#if __has_builtin(__builtin_amdgcn_mfma_f32_16x16x16bf16_1k)
  return __builtin_amdgcn_mfma_f32_16x16x16bf16_1k(a, b, c, 0, 0, 0);
#else
  f32x4 d;
  asm volatile("v_mfma_f32_16x16x16_bf16 %0, %1, %2, %3\n\ts_nop 4"
               : "=v"(d) : "v"(a), "v"(b), "v"(c));
  return d;
#endif
}

__device__ __forceinline__ void gl2lds16(const u16* g, u16* l) {
  __builtin_amdgcn_global_load_lds((const __attribute__((address_space(1))) void*)g,
                                   (__attribute__((address_space(3))) void*)l, 16, 0, 0);
}

// fragment cell address (u16 units) with bank-spreading XOR swizzle (attn Kf)
__device__ __forceinline__ int fragaddr(int frag, int lane) {
  return (frag * 64 + (lane ^ (frag & 7))) * 8;
}

// ---------------- fp32 -> bf16 conversion ------------------------------------
__global__ __launch_bounds__(256) void cvt_all(
    const float* __restrict__ x, const float* __restrict__ w1f,
    const float* __restrict__ w2f, u16* __restrict__ xo,
    u16* __restrict__ w1o, u16* __restrict__ w2o) {
  const int NX = 4194304, NW1 = 196608, NW2 = 65536;
  int i = blockIdx.x * 256 + threadIdx.x;
  const float* src; u16* dst; int j;
  if (i < NX)                  { src = x;   dst = xo;  j = i; }
  else if (i < NX + NW1)       { src = w1f; dst = w1o; j = i - NX; }
  else if (i < NX + NW1 + NW2) { src = w2f; dst = w2o; j = i - NX - NW1; }
  else return;
  float4 f = ((const float4*)src)[j];
  uint2 o;
  o.x = (u32)f2bf(f.x) | ((u32)f2bf(f.y) << 16);
  o.y = (u32)f2bf(f.z) | ((u32)f2bf(f.w) << 16);
  ((uint2*)dst)[j] = o;
}

// ---------------- 256x256 8-phase GEMM core (TRANSPOSED acc) -----------------
// C = A[256x512] * B[256x512]^T; acc[mf][nf] holds the transposed D fragment:
// element [i] = C[token = wm*128+mf*16+cx][col = wn*64+nf*16+g*4+i].
__device__ __forceinline__ void gemm256_core(
    const u16* __restrict__ A, const u16* __restrict__ B,
    int m0, int n0, u16* lds, f32x4 acc[8][4]) {
  const int NT = 8;                       // K = 512, BK = 64
  int tid = threadIdx.x, wave = tid >> 6, lane = tid & 63;
  int wm = wave >> 2, wn = wave & 3;

  int ch0 = tid, ch1 = tid + 512;
  int row0 = ch0 >> 2, row1 = ch1 >> 2;
  int cg0 = (ch0 & 3) ^ (row0 & 3) ^ ((row0 >> 2) & 3);
  int cg1 = (ch1 & 3) ^ (row1 & 3) ^ ((row1 >> 2) & 3);
  const u16* Ag0 = A + (size_t)(m0 + row0) * 512 + cg0 * 8;
  const u16* Ag1 = A + (size_t)(m0 + row1) * 512 + cg1 * 8;
  const u16* Bg0 = B + (size_t)(n0 + row0) * 512 + cg0 * 8;
  const u16* Bg1 = B + (size_t)(n0 + row1) * 512 + cg1 * 8;
  int ldsu0 = wave * 64 * 8;              // HW adds lane*16B
  int ldsu1 = (512 + wave * 64) * 8;

  int frag_off = (lane & 15) * 32 +
                 (((lane >> 4) ^ (lane & 3) ^ ((lane >> 2) & 3)) << 3);
  int abase = wm * 4096 + frag_off;        // + mf*512 + kh*16384 + p*32768
  int bbase = 8192 + wn * 2048 + frag_off; // + nf*512 + kh*16384 + p*32768

#define STAGE(h)                                                             \
  do {                                                                       \
    if ((h) < NT * 4) {                                                      \
      int T_ = (h) >> 2, kh_ = ((h) >> 1) & 1, isB_ = (h) & 1;               \
      int ko_ = T_ * 64 + kh_ * 32;                                          \
      u16* d_ = lds + (T_ & 1) * 32768 + kh_ * 16384 + isB_ * 8192;          \
      gl2lds16((isB_ ? Bg0 : Ag0) + ko_, d_ + ldsu0);                        \
      gl2lds16((isB_ ? Bg1 : Ag1) + ko_, d_ + ldsu1);                        \
    }                                                                        \
  } while (0)

#define LDA(dst, mf, kh, p)                                                  \
  dst = *(const short8*)(lds + (p) * 32768 + (kh) * 16384 + abase + (mf) * 512)
#define LDB(dst, nf, kh, p)                                                  \
  dst = *(const short8*)(lds + (p) * 32768 + (kh) * 16384 + bbase + (nf) * 512)

// transposed: acc[m][n] = mfma(b_n, a_m, acc[m][n])
#define MM16(M0)                                                                                   \
  __builtin_amdgcn_s_setprio(1);                                                                   \
  acc[(M0)+0][0] = __builtin_amdgcn_mfma_f32_16x16x32_bf16(b0, a0, acc[(M0)+0][0], 0, 0, 0);       \
  acc[(M0)+0][1] = __builtin_amdgcn_mfma_f32_16x16x32_bf16(b1, a0, acc[(M0)+0][1], 0, 0, 0);       \
  acc[(M0)+0][2] = __builtin_amdgcn_mfma_f32_16x16x32_bf16(b2, a0, acc[(M0)+0][2], 0, 0, 0);       \
  acc[(M0)+0][3] = __builtin_amdgcn_mfma_f32_16x16x32_bf16(b3, a0, acc[(M0)+0][3], 0, 0, 0);       \
  acc[(M0)+1][0] = __builtin_amdgcn_mfma_f32_16x16x32_bf16(b0, a1, acc[(M0)+1][0], 0, 0, 0);       \
  acc[(M0)+1][1] = __builtin_amdgcn_mfma_f32_16x16x32_bf16(b1, a1, acc[(M0)+1][1], 0, 0, 0);       \
  acc[(M0)+1][2] = __builtin_amdgcn_mfma_f32_16x16x32_bf16(b2, a1, acc[(M0)+1][2], 0, 0, 0);       \
  acc[(M0)+1][3] = __builtin_amdgcn_mfma_f32_16x16x32_bf16(b3, a1, acc[(M0)+1][3], 0, 0, 0);       \
  acc[(M0)+2][0] = __builtin_amdgcn_mfma_f32_16x16x32_bf16(b0, a2, acc[(M0)+2][0], 0, 0, 0);       \
  acc[(M0)+2][1] = __builtin_amdgcn_mfma_f32_16x16x32_bf16(b1, a2, acc[(M0)+2][1], 0, 0, 0);       \
  acc[(M0)+2][2] = __builtin_amdgcn_mfma_f32_16x16x32_bf16(b2, a2, acc[(M0)+2][2], 0, 0, 0);       \
  acc[(M0)+2][3] = __builtin_amdgcn_mfma_f32_16x16x32_bf16(b3, a2, acc[(M0)+2][3], 0, 0, 0);       \
  acc[(M0)+3][0] = __builtin_amdgcn_mfma_f32_16x16x32_bf16(b0, a3, acc[(M0)+3][0], 0, 0, 0);       \
  acc[(M0)+3][1] = __builtin_amdgcn_mfma_f32_16x16x32_bf16(b1, a3, acc[(M0)+3][1], 0, 0, 0);       \
  acc[(M0)+3][2] = __builtin_amdgcn_mfma_f32_16x16x32_bf16(b2, a3, acc[(M0)+3][2], 0, 0, 0);       \
  acc[(M0)+3][3] = __builtin_amdgcn_mfma_f32_16x16x32_bf16(b3, a3, acc[(M0)+3][3], 0, 0, 0);       \
  __builtin_amdgcn_s_setprio(0)

  STAGE(0); STAGE(1); STAGE(2); STAGE(3); STAGE(4);
  asm volatile("s_waitcnt vmcnt(6)" ::: "memory");
  __builtin_amdgcn_s_barrier();

#pragma unroll 1
  for (int kt = 0; kt < NT; ++kt) {
    int p = kt & 1;
    int hb = kt * 4 + 5;
    short8 a0, a1, a2, a3, b0, b1, b2, b3;
    LDA(a0, 0, 0, p); LDA(a1, 1, 0, p); LDA(a2, 2, 0, p); LDA(a3, 3, 0, p);
    LDB(b0, 0, 0, p); LDB(b1, 1, 0, p); LDB(b2, 2, 0, p); LDB(b3, 3, 0, p);
    STAGE(hb);
    __builtin_amdgcn_s_barrier();
    asm volatile("s_waitcnt lgkmcnt(0)" ::: "memory");
    MM16(0);
    __builtin_amdgcn_s_barrier();
    LDA(a0, 4, 0, p); LDA(a1, 5, 0, p); LDA(a2, 6, 0, p); LDA(a3, 7, 0, p);
    STAGE(hb + 1);
    __builtin_amdgcn_s_barrier();
    asm volatile("s_waitcnt lgkmcnt(0)" ::: "memory");
    MM16(4);
    if (kt == NT - 1) asm volatile("s_waitcnt vmcnt(0)" ::: "memory");
    else              asm volatile("s_waitcnt vmcnt(6)" ::: "memory");
    __builtin_amdgcn_s_barrier();
    LDA(a0, 0, 1, p); LDA(a1, 1, 1, p); LDA(a2, 2, 1, p); LDA(a3, 3, 1, p);
    LDB(b0, 0, 1, p); LDB(b1, 1, 1, p); LDB(b2, 2, 1, p); LDB(b3, 3, 1, p);
    STAGE(hb + 2);
    __builtin_amdgcn_s_barrier();
    asm volatile("s_waitcnt lgkmcnt(0)" ::: "memory");
    MM16(0);
    __builtin_amdgcn_s_barrier();
    LDA(a0, 4, 1, p); LDA(a1, 5, 1, p); LDA(a2, 6, 1, p); LDA(a3, 7, 1, p);
    STAGE(hb + 3);
    __builtin_amdgcn_s_barrier();
    asm volatile("s_waitcnt lgkmcnt(0)" ::: "memory");
    MM16(4);
    if (kt == NT - 2)     asm volatile("s_waitcnt vmcnt(4)" ::: "memory");
    else if (kt < NT - 2) asm volatile("s_waitcnt vmcnt(6)" ::: "memory");
    __builtin_amdgcn_s_barrier();
  }
#undef STAGE
#undef LDA
#undef LDB
#undef MM16
}

// ---------------- GEMM1: qkv = x @ qkv_w^T + b; scatter q(scaled)/k/v --------
__global__ __launch_bounds__(512, 2) void gemm_qkv256(
    const u16* __restrict__ A, const u16* __restrict__ B,
    const float* __restrict__ qkvb, u16* __restrict__ qb,
    u16* __restrict__ kb, u16* __restrict__ vb) {
  __shared__ __align__(16) u16 lds[65536];   // 128 KiB
  f32x4 acc[8][4];
#pragma unroll
  for (int a = 0; a < 8; ++a)
#pragma unroll
    for (int c = 0; c < 4; ++c) acc[a][c] = (f32x4){0.f, 0.f, 0.f, 0.f};
  // XCD-chunked bijective swizzle (768 % 8 == 0)
  int bid = blockIdx.x;
  int wg = (bid & 7) * 96 + (bid >> 3);
  int m0 = (wg / 6) * 256, n0 = (wg % 6) * 256;
  gemm256_core(A, B, m0, n0, lds, acc);

  int tid = threadIdx.x, wave = tid >> 6, lane = tid & 63;
  int wm = wave >> 2, wn = wave & 3;
  int cx = lane & 15, g = lane >> 4;

  // ---- stage C tile in LDS: one b64 write per (mf,nf) ----
  __syncthreads();
  float sc = (n0 < 512) ? 0.125f : 1.f;      // q-scale, uniform per tile
  float4 bvn[4];
#pragma unroll
  for (int nf = 0; nf < 4; ++nf)
    bvn[nf] = *(const float4*)(qkvb + n0 + wn * 64 + nf * 16 + g * 4);
#pragma unroll
  for (int mf = 0; mf < 8; ++mf) {
    int r = wm * 128 + mf * 16 + cx;
    int swz = r & 7;                         // low row bits -> 2-way only
#pragma unroll
    for (int nf = 0; nf < 4; ++nf) {
      int c0 = wn * 64 + nf * 16 + g * 4;    // 4 consecutive cols
      int c16 = (c0 >> 3) ^ swz;
      f32x4 v = acc[mf][nf];
      u32 w0 = cvtpk((v[0] + bvn[nf].x) * sc, (v[1] + bvn[nf].y) * sc);
      u32 w1 = cvtpk((v[2] + bvn[nf].z) * sc, (v[3] + bvn[nf].w) * sc);
      *(uint2*)(lds + r * 256 + c16 * 8 + (c0 & 7)) = make_uint2(w0, w1);
    }
  }
  __syncthreads();

  // ---- copy-out: 4 h-group slabs, each 256n x 64d contiguous --------------
  int b = m0 >> 8;                           // tile is one window
  int nrow = tid >> 3, dc = tid & 7;
#pragma unroll
  for (int j = 0; j < 16; ++j) {
    const int hg = j >> 2;
    int gcol = n0 + hg * 64;
    int which = gcol >> 9;
    int h = (gcol >> 6) & 7;
    u16* dst = (which == 0 ? qb : (which == 1 ? kb : vb)) +
               (size_t)(b * 8 + h) * 16384;
    int n = (j & 3) * 64 + nrow;
    int c16 = (hg * 8 + dc) ^ (n & 7);
    uint4 val = *(const uint4*)(lds + n * 256 + c16 * 8);
    *(uint4*)(dst + n * 64 + dc * 8) = val;
  }
}

// ---------------- GEMM2: out = attnout @ proj_w^T + proj_b (fp32 out) --------
__global__ __launch_bounds__(512, 2) void gemm_proj256(
    const u16* __restrict__ A, const u16* __restrict__ B,
    const float* __restrict__ pb, float* __restrict__ out) {
  __shared__ __align__(16) u16 lds[65536];   // 128 KiB
  f32x4 acc[8][4];
#pragma unroll
  for (int a = 0; a < 8; ++a)
#pragma unroll
    for (int c = 0; c < 4; ++c) acc[a][c] = (f32x4){0.f, 0.f, 0.f, 0.f};
  int bid = blockIdx.x;
  int wg = (bid & 7) * 32 + (bid >> 3);      // 256 % 8 == 0, bijective
  int m0 = (wg >> 1) * 256, n0 = (wg & 1) * 256;
  gemm256_core(A, B, m0, n0, lds, acc);

  int tid = threadIdx.x, wave = tid >> 6, lane = tid & 63;
  int wm = wave >> 2, wn = wave & 3;
  int cx = lane & 15, g = lane >> 4;
  int cb = n0 + wn * 64 + g * 4;
  float4 bv[4];
#pragma unroll
  for (int nf = 0; nf < 4; ++nf) bv[nf] = *(const float4*)(pb + cb + nf * 16);
  int r0 = m0 + wm * 128 + cx;
#pragma unroll
  for (int mf = 0; mf < 8; ++mf) {
    size_t rb = (size_t)(r0 + mf * 16) * 512;
#pragma unroll
    for (int nf = 0; nf < 4; ++nf) {
      f32x4 v = acc[mf][nf];
      float4 o = make_float4(v[0] + bv[nf].x, v[1] + bv[nf].y,
                             v[2] + bv[nf].z, v[3] + bv[nf].w);
      *(float4*)(out + rb + cb + nf * 16) = o;
    }
  }
}

// ---------------- qconv: Q' = Q + conv15_n(Q), in place per (b,h) window -----
__global__ __launch_bounds__(256) void qconv(u16* __restrict__ qb,
                                             const float* __restrict__ pe_w) {
  __shared__ __align__(16) u16 Ql[256 * 72];
  __shared__ float w[15];
  int bh = blockIdx.x, h = bh & 7, tid = threadIdx.x;
  const uint4* src = (const uint4*)(qb + (size_t)bh * 16384);
#pragma unroll
  for (int it = 0; it < 8; ++it) {
    int idx = tid + it * 256;
    int row = idx >> 3, c = (idx & 7) * 8;
    *(uint4*)(Ql + row * 72 + c) = src[idx];
  }
  if (tid < 15) w[tid] = pe_w[h * 15 + tid] + (tid == 7 ? 1.f : 0.f);  // identity folded
  __syncthreads();
  int dg = (tid & 15) * 4, nb4 = tid >> 4;
  uint2* dst = (uint2*)(qb + (size_t)bh * 16384);
#pragma unroll
  for (int i = 0; i < 16; ++i) {
    int n = nb4 + i * 16;
    float a0 = 0.f, a1 = 0.f, a2 = 0.f, a3 = 0.f;
#pragma unroll
    for (int t = 0; t < 15; ++t) {
      int nn = n + t - 7;
      if (nn < 0 || nn > 255) continue;
      uint2 rv = *(const uint2*)(Ql + nn * 72 + dg);
      float wt = w[t];
      a0 += wt * bf2f(rv.x & 0xffff); a1 += wt * bf2f(rv.x >> 16);
      a2 += wt * bf2f(rv.y & 0xffff); a3 += wt * bf2f(rv.y >> 16);
    }
    uint2 pv;
    pv.x = (u32)f2bf(a0) | ((u32)f2bf(a1) << 16);
    pv.y = (u32)f2bf(a2) | ((u32)f2bf(a3) << 16);
    dst[(n * 64 + dg) >> 2] = pv;
  }
}

// ---------------- attention: 1 wg (512 thr) per (b,h); barrier-free loop -----
// Swapped QK^T (mfma(K,Q) -> S^T: lane owns q=qbase+cx, 32 lane-local
// k-values). PV runs K=16 (mfma_f32_16x16x16_bf16): lane's S^T rows
// k=mt*16+g*4+i are EXACTLY the K=16 B-operand layout -> P packed in-register
// (2 cvt_pk), no LDS roundtrip. Vf stored as 64 K=16 A-frags (uint2/lane,
// linear, conflict-free). Softmax state and O live in the q=cx lane domain.
__global__ __launch_bounds__(512, 2) void attn_win(
    const u16* __restrict__ qb, const u16* __restrict__ kb,
    const u16* __restrict__ vb, const float* __restrict__ pe_b,
    const float* __restrict__ rpb, u16* __restrict__ attnout) {
  __shared__ __align__(16) u16 KfPs[17408];   // Vtmp(256x68) -> Kf(16384)
  __shared__ __align__(16) u16 Vf[16384];     // 64 K=16 A-frags (dt,mc)
  __shared__ float biasl[961];

  int bh = blockIdx.x, b = bh >> 3, h = bh & 7;
  int tid = threadIdx.x, wave = tid >> 6, lane = tid & 63;
  int cx = lane & 15, g = lane >> 4;

  const uint4* kg = (const uint4*)(kb + (size_t)bh * 16384);
  const uint4* vg = (const uint4*)(vb + (size_t)bh * 16384);
  const u16* qgb = qb + (size_t)bh * 16384;

  // Q fragments for both it2 hoisted: latency hides under staging barriers
  short8 qfr0a = *(const short8*)(qgb + (0 * 128 + wave * 16 + cx) * 64 + g * 8);
  short8 qfr0b = *(const short8*)(qgb + (0 * 128 + wave * 16 + cx) * 64 + 32 + g * 8);
  short8 qfr1a = *(const short8*)(qgb + (1 * 128 + wave * 16 + cx) * 64 + g * 8);
  short8 qfr1b = *(const short8*)(qgb + (1 * 128 + wave * 16 + cx) * 64 + 32 + g * 8);

  // K prefetch into registers (KfPs is occupied by Vtmp until Vf built)
  uint4 kreg[4];
#pragma unroll
  for (int it = 0; it < 4; ++it) kreg[it] = kg[tid + it * 512];

  // ---- stage V rows -> Vtmp (stride 68, bank-spread) + bias (pe_b folded) ---
  u16* Vtmp = KfPs;
#pragma unroll
  for (int it = 0; it < 4; ++it) {
    int idx = tid + it * 512;
    uint4 v = vg[idx];
    int row = idx >> 3, c8 = (idx & 7) * 8;
    *(uint2*)(Vtmp + row * 68 + c8)     = make_uint2(v.x, v.y);
    *(uint2*)(Vtmp + row * 68 + c8 + 4) = make_uint2(v.z, v.w);
  }
  {
    float peb = pe_b[h];
    for (int i = tid; i < 961; i += 512) biasl[i] = rpb[i * 8 + h] + peb;
  }
  __syncthreads();

  // ---- build Vf K=16 A-frags: frag=dt*16+mc; lane holds
  // V[mc*16 + (lane>>4)*4 + j][dt*16 + (lane&15)], j=0..3 (one uint2) ----
#pragma unroll
  for (int it = 0; it < 8; ++it) {
    int o = tid + it * 512;                  // 4096 slots
    int frag = o >> 6, lanep = o & 63;
    int d = (frag >> 4) * 16 + (lanep & 15);
    int mb = (frag & 15) * 16 + (lanep >> 4) * 4;
    uint2 pk;
    pk.x = (u32)Vtmp[(mb + 0) * 68 + d] | ((u32)Vtmp[(mb + 1) * 68 + d] << 16);
    pk.y = (u32)Vtmp[(mb + 2) * 68 + d] | ((u32)Vtmp[(mb + 3) * 68 + d] << 16);
    *(uint2*)(Vf + frag * 256 + lanep * 4) = pk;
  }
  __syncthreads();

  // ---- write K fragments from registers ----
  u16* Kf = KfPs;
#pragma unroll
  for (int it = 0; it < 4; ++it) {
    int idx = tid + it * 512;
    int n = idx >> 3, k8 = idx & 7;
    int frag = (n >> 4) * 2 + (k8 >> 2);
    int lanep = (n & 15) + 16 * (k8 & 3);
    *(uint4*)(Kf + (frag * 64 + (lanep ^ (frag & 7))) * 8) = kreg[it];
  }
  __syncthreads();   // last barrier — main loop is barrier-free

#pragma unroll
  for (int it2 = 0; it2 < 2; ++it2) {
    short8 qf0 = it2 ? qfr1a : qfr0a;
    short8 qf1 = it2 ? qfr1b : qfr0b;
    int qbase = it2 * 128 + wave * 16;

    float m_run = -1e30f, l_run = 0.f;
    f32x4 oacc[4];
#pragma unroll
    for (int dt = 0; dt < 4; ++dt) oacc[dt] = (f32x4){0.f, 0.f, 0.f, 0.f};

#pragma unroll
    for (int c = 0; c < 2; ++c) {
      // ---- QK^T (swapped): acc[mt] = S^T rows k, cols q=cx ----
      f32x4 acc[8];
#pragma unroll
      for (int mt = 0; mt < 8; ++mt) acc[mt] = (f32x4){0.f, 0.f, 0.f, 0.f};
      __builtin_amdgcn_s_setprio(1);
#pragma unroll
      for (int mt = 0; mt < 8; ++mt) {
        int fr = (c * 8 + mt) * 2;
        short8 k0 = *(const short8*)(Kf + fragaddr(fr, lane));
        short8 k1 = *(const short8*)(Kf + fragaddr(fr + 1, lane));
        acc[mt] = __builtin_amdgcn_mfma_f32_16x16x32_bf16(k0, qf0, acc[mt], 0, 0, 0);
        acc[mt] = __builtin_amdgcn_mfma_f32_16x16x32_bf16(k1, qf1, acc[mt], 0, 0, 0);
      }
      __builtin_amdgcn_s_setprio(0);

      // ---- bias add (lane-local k) ----
      // k = c*128 + mt*16 + g*4 + i ; q = qbase + cx
      int nb2 = (it2 * 8 + wave - c * 8 + 15) * 31 + cx - g * 4 + 15;
#pragma unroll
      for (int mt = 0; mt < 8; ++mt) {
        const float* bp = biasl + (nb2 - 31 * mt);
        acc[mt][0] += bp[0];  acc[mt][1] += bp[-1];
        acc[mt][2] += bp[-2]; acc[mt][3] += bp[-3];
      }

      // ---- online softmax: lane-local tree + 2 shfl ----
      float mx = fmaxf(fmaxf(acc[0][0], acc[0][1]), fmaxf(acc[0][2], acc[0][3]));
#pragma unroll
      for (int mt = 1; mt < 8; ++mt)
        mx = fmaxf(mx, fmaxf(fmaxf(acc[mt][0], acc[mt][1]),
                             fmaxf(acc[mt][2], acc[mt][3])));
      mx = fmaxf(mx, __shfl_xor(mx, 16));
      mx = fmaxf(mx, __shfl_xor(mx, 32));
      float mnew = fmaxf(m_run, mx);
      float al = __expf(m_run - mnew);
      float s = 0.f;
#pragma unroll
      for (int mt = 0; mt < 8; ++mt)
#pragma unroll
        for (int i = 0; i < 4; ++i) {
          float e = __expf(acc[mt][i] - mnew);
          acc[mt][i] = e; s += e;
        }
      s += __shfl_xor(s, 16);
      s += __shfl_xor(s, 32);
      l_run = l_run * al + s;
      m_run = mnew;

      // alpha rescale: oacc cols are q=cx -> lane-local, no shuffles
#pragma unroll
      for (int dt = 0; dt < 4; ++dt)
#pragma unroll
        for (int i = 0; i < 4; ++i) oacc[dt][i] *= al;

      // ---- PV (K=16, lane-local P): pa = 2x cvt_pk of acc[mt] ----
#pragma unroll
      for (int mt = 0; mt < 8; ++mt) {
        union { uint2 u; s4b s; } cv;
        cv.u = make_uint2(cvtpk(acc[mt][0], acc[mt][1]),
                          cvtpk(acc[mt][2], acc[mt][3]));
        s4b pa = cv.s;
        __builtin_amdgcn_s_setprio(1);
#pragma unroll
        for (int dt = 0; dt < 4; ++dt) {
          s4b vf = *(const s4b*)(Vf + (dt * 16 + c * 8 + mt) * 256 + lane * 4);
          oacc[dt] = mfma16(vf, pa, oacc[dt]);
        }
        __builtin_amdgcn_s_setprio(0);
      }
    }

    // ---- epilogue: normalize (lane-local) + packed store ----
    float inv = 1.f / l_run;
    u16* ao = attnout + ((size_t)b * 256 + qbase + cx) * 512 + h * 64;
#pragma unroll
    for (int dt = 0; dt < 4; ++dt) {
      u32 w0 = cvtpk(oacc[dt][0] * inv, oacc[dt][1] * inv);
      u32 w1 = cvtpk(oacc[dt][2] * inv, oacc[dt][3] * inv);
      *(uint2*)(ao + dt * 16 + g * 4) = make_uint2(w0, w1);
    }
  }
}

extern "C" void kernel_launch(void* const* d_in, const int* in_sizes, int n_in,
                              void* d_out, int out_size, void* d_ws, size_t ws_size,
                              hipStream_t stream) {
  const float* x      = (const float*)d_in[0];
  const float* qkv_w  = (const float*)d_in[1];
  const float* qkv_b  = (const float*)d_in[2];
  const float* pe_w   = (const float*)d_in[3];
  const float* pe_b   = (const float*)d_in[4];
  const float* rpb    = (const float*)d_in[5];
  const float* proj_w = (const float*)d_in[6];
  const float* proj_b = (const float*)d_in[7];
  float* out = (float*)d_out;
  char* ws = (char*)d_ws;

  size_t off = 0;
  u16* xbf = (u16*)(ws + off); off += (size_t)16777216 * 2;  // also attnout
  u16* w1  = (u16*)(ws + off); off += (size_t)786432 * 2;
  u16* w2  = (u16*)(ws + off); off += (size_t)262144 * 2;
  u16* qb  = (u16*)(ws + off); off += (size_t)16777216 * 2;
  u16* kb  = (u16*)(ws + off); off += (size_t)16777216 * 2;
  u16* vb  = (u16*)(ws + off); off += (size_t)16777216 * 2;

  hipLaunchKernelGGL(cvt_all, dim3(17408), dim3(256), 0, stream,
                     x, qkv_w, proj_w, xbf, w1, w2);
  hipLaunchKernelGGL(gemm_qkv256, dim3(768), dim3(512), 0, stream,
                     xbf, w1, qkv_b, qb, kb, vb);
  hipLaunchKernelGGL(qconv, dim3(1024), dim3(256), 0, stream, qb, pe_w);
  hipLaunchKernelGGL(attn_win, dim3(1024), dim3(512), 0, stream,
                     qb, kb, vb, pe_b, rpb, xbf);
  hipLaunchKernelGGL(gemm_proj256, dim3(256), dim3(512), 0, stream,
                     xbf, w2, proj_b, out);
}